// Round 13
// baseline (990.550 us; speedup 1.0000x reference)
//
#include <hip/hip_runtime.h>
#include <hip/hip_bf16.h>
#include <stdint.h>
#include <stddef.h>

#define E_ 8
#define C_ 4096
#define H_ 1024
#define I_ 4096

typedef short s16;
typedef __attribute__((ext_vector_type(8))) short short8;   // 8 bf16 (4 VGPRs)
typedef __attribute__((ext_vector_type(4))) short short4v;  // 4 bf16 (8B)
typedef __attribute__((ext_vector_type(4))) float f32x4;    // MFMA C/D frag
typedef __attribute__((ext_vector_type(4))) float float4v;

__device__ __forceinline__ s16 f2bf(float f) {
  union { __hip_bfloat16 h; s16 s; } u;
  u.h = __float2bfloat16(f);
  return u.s;
}

// async global->LDS, 16B per lane. LDS dest is wave-uniform base + lane*16.
__device__ __forceinline__ void gload16(const void* gsrc, void* ldst) {
  __builtin_amdgcn_global_load_lds(
      (const __attribute__((address_space(1))) void*)gsrc,
      (__attribute__((address_space(3))) void*)ldst, 16, 0, 0);
}

// ---------------------------------------------------------------------------
// prep: expert = blockIdx.y   (FROZEN since r3; ~HBM roofline)
// z=0: x fp32 -> bf16
// z=1: Wg [H][I] -> interleaved Wgu rows (gate block)   [2I][H] bf16
// z=2: Wu -> interleaved Wgu rows (up block)
// z=3: Wd [I][H] -> WdT [H][I] bf16
// Interleave: real col i -> row (i&~15)*2 + (i&15) (+16 for up).
// ---------------------------------------------------------------------------
__global__ __launch_bounds__(256) void prep_kernel(
    const float* __restrict__ x, const float* __restrict__ Wg,
    const float* __restrict__ Wu, const float* __restrict__ Wd,
    s16* __restrict__ xb, s16* __restrict__ Wgu, s16* __restrict__ WdT)
{
  __shared__ float tile[64][65];
  const int t = threadIdx.x;
  const int z = blockIdx.z;
  const size_t e = blockIdx.y;

  if (z == 0) {
    size_t base = e * (size_t)C_ * H_ + ((size_t)blockIdx.x * 256 + t) * 16;
    for (int j = 0; j < 16; j += 8) {
      float4v v0 = *(const float4v*)(x + base + j);
      float4v v1 = *(const float4v*)(x + base + j + 4);
      s16 o[8];
      o[0] = f2bf(v0[0]); o[1] = f2bf(v0[1]); o[2] = f2bf(v0[2]); o[3] = f2bf(v0[3]);
      o[4] = f2bf(v1[0]); o[5] = f2bf(v1[1]); o[6] = f2bf(v1[2]); o[7] = f2bf(v1[3]);
      *(short8*)(xb + base + j) = *(short8*)o;
    }
    return;
  }

  const float* src; int Cc;
  if (z == 1)      { src = Wg + e * (size_t)H_ * I_; Cc = I_; }
  else if (z == 2) { src = Wu + e * (size_t)H_ * I_; Cc = I_; }
  else             { src = Wd + e * (size_t)H_ * I_; Cc = H_; }

  const int tpr  = Cc >> 6;
  const int trow = blockIdx.x / tpr;
  const int tcol = blockIdx.x % tpr;

  const int c = t & 63, rq = t >> 6;
  for (int i = 0; i < 16; ++i) {
    int r = rq * 16 + i;
    tile[r][c] = src[(size_t)(trow * 64 + r) * Cc + tcol * 64 + c];
  }
  __syncthreads();

  const int ro = t >> 2, cb = (t & 3) * 16;
  s16 o[16];
  for (int j = 0; j < 16; ++j) o[j] = f2bf(tile[cb + j][ro]);

  const int i0 = tcol * 64 + ro;
  s16* op;
  if (z == 3) {
    op = WdT + e * (size_t)H_ * I_ + (size_t)i0 * I_ + trow * 64 + cb;
  } else {
    int grow = ((i0 & ~15) << 1) + (i0 & 15) + ((z == 2) ? 16 : 0);
    op = Wgu + e * (size_t)2 * I_ * H_ + (size_t)grow * H_ + trow * 64 + cb;
  }
  *(short8*)op       = *(short8*)&o[0];
  *(short8*)(op + 8) = *(short8*)&o[8];
}

// ===========================================================================
// Shared: swapped-operand (D^T) 16x16x32 MFMA. D^T map: out-row = ... +
// m*16 + (lane&15), out-col = ... + n*16 + (lane>>4)*4 + q (vector store).
// ===========================================================================
#define MFMA16(MH, A0, A1, A2, A3)                                                            \
  acc[(MH)*4+0][0] = __builtin_amdgcn_mfma_f32_16x16x32_bf16(bf[0], A0, acc[(MH)*4+0][0],0,0,0); \
  acc[(MH)*4+0][1] = __builtin_amdgcn_mfma_f32_16x16x32_bf16(bf[1], A0, acc[(MH)*4+0][1],0,0,0); \
  acc[(MH)*4+0][2] = __builtin_amdgcn_mfma_f32_16x16x32_bf16(bf[2], A0, acc[(MH)*4+0][2],0,0,0); \
  acc[(MH)*4+0][3] = __builtin_amdgcn_mfma_f32_16x16x32_bf16(bf[3], A0, acc[(MH)*4+0][3],0,0,0); \
  acc[(MH)*4+1][0] = __builtin_amdgcn_mfma_f32_16x16x32_bf16(bf[0], A1, acc[(MH)*4+1][0],0,0,0); \
  acc[(MH)*4+1][1] = __builtin_amdgcn_mfma_f32_16x16x32_bf16(bf[1], A1, acc[(MH)*4+1][1],0,0,0); \
  acc[(MH)*4+1][2] = __builtin_amdgcn_mfma_f32_16x16x32_bf16(bf[2], A1, acc[(MH)*4+1][2],0,0,0); \
  acc[(MH)*4+1][3] = __builtin_amdgcn_mfma_f32_16x16x32_bf16(bf[3], A1, acc[(MH)*4+1][3],0,0,0); \
  acc[(MH)*4+2][0] = __builtin_amdgcn_mfma_f32_16x16x32_bf16(bf[0], A2, acc[(MH)*4+2][0],0,0,0); \
  acc[(MH)*4+2][1] = __builtin_amdgcn_mfma_f32_16x16x32_bf16(bf[1], A2, acc[(MH)*4+2][1],0,0,0); \
  acc[(MH)*4+2][2] = __builtin_amdgcn_mfma_f32_16x16x32_bf16(bf[2], A2, acc[(MH)*4+2][2],0,0,0); \
  acc[(MH)*4+2][3] = __builtin_amdgcn_mfma_f32_16x16x32_bf16(bf[3], A2, acc[(MH)*4+2][3],0,0,0); \
  acc[(MH)*4+3][0] = __builtin_amdgcn_mfma_f32_16x16x32_bf16(bf[0], A3, acc[(MH)*4+3][0],0,0,0); \
  acc[(MH)*4+3][1] = __builtin_amdgcn_mfma_f32_16x16x32_bf16(bf[1], A3, acc[(MH)*4+3][1],0,0,0); \
  acc[(MH)*4+3][2] = __builtin_amdgcn_mfma_f32_16x16x32_bf16(bf[2], A3, acc[(MH)*4+3][2],0,0,0); \
  acc[(MH)*4+3][3] = __builtin_amdgcn_mfma_f32_16x16x32_bf16(bf[3], A3, acc[(MH)*4+3][3],0,0,0);

#define VMW4 asm volatile("s_waitcnt vmcnt(4)" ::: "memory");
#define VMW8 asm volatile("s_waitcnt vmcnt(8)" ::: "memory");

// ===========================================================================
// gemm_gu: gateup, 256x256 tile, BK=32, 8 waves, QUAD-buffered LDS
// (A 4x16KB | B 4x16KB = 128 KiB), ONE barrier per BK32-phase.
// Folded LDS layout per 16KB tile (r8/r9 HW-verified, conflicts=0):
// logical [256 rows][32 k] stored as [128 phys rows][64 elems]:
//   phys(R,c) = (R>>1)*64 + (((R&1)*32 + c) ^ (((R>>1)&7)<<3))
// Phase t: {12 ds_read of buf[t&3]; stage tile t+3 -> buf[(t+3)&3];
//   lgkmcnt(0); 32 MFMA; vmcnt(8); s_barrier}.
// Ledger: stage(p+3) issued at p-top; VMW8 at p-tail keeps newest 8 loads
// (stages p+2, p+3) -> drains stage(p+1) BEFORE (p+1)-top reads it; barrier
// publishes. Slack for stage(t): issued (t-3)-top, drained (t-1)-tail ~2.8
// phases (~7500 cyc) - covers HBM latency (the r12 structure gave only
// ~1375 cyc). Buffer-overwrite safety: stage at t-top hits buf[(t-1)&3],
// whose readers' lgkmcnt(0) completed before (t-1)'s closing barrier.
// ===========================================================================
#define LDA32(BUF, MH, M) \
  (*(const short8*)(shm + (BUF)*8192 + aBase + (MH)*2048 + (M)*512))
#define LDB32(BUF, N) \
  (*(const short8*)(shm + 32768 + (BUF)*8192 + bBase + (N)*512))

__global__ __launch_bounds__(512, 2) void gemm_gu(
    const s16* __restrict__ Abase, const s16* __restrict__ Bbase,
    s16* __restrict__ HOut)
{
  constexpr int K  = H_;         // 1024
  constexpr int NB = 2 * I_;     // 8192
  constexpr int NT = K / 32;     // 32 BK32-tiles

  __shared__ s16 shm[65536];     // 128 KiB: A 4x8192 elems | B 4x8192 elems

  const int tid  = threadIdx.x;
  const int wave = tid >> 6, lane = tid & 63;
  const int e    = blockIdx.z;

  // r4 fetch-optimal per-XCD partition: 8bn x 8bm sub-grid per XCD.
  const int bid = blockIdx.x;    // 0..511 per expert
  const int xcd = bid & 7;
  const int idx = bid >> 3;      // 0..63
  const int bn  = (xcd & 3) * 8 + (idx & 7);   // 0..31
  const int bm  = (xcd >> 2) * 8 + (idx >> 3); // 0..15

  const s16* A = Abase + (size_t)e * C_ * K + (size_t)bm * 256 * K;
  const s16* B = Bbase + (size_t)e * NB * K + (size_t)bn * 256 * K;

  const int wm  = (wave >> 2) * 128;
  const int wn  = (wave & 3) * 64;
  const int lr  = lane & 15;
  const int lkb = (lane >> 4) * 8;

  // read-side folded-swizzle constants (r8/r9, HW-verified conflict-free)
  const int qA    = (((lr & 1) << 5) | lkb) ^ ((lr >> 1) << 3);
  const int aBase = (wm << 5) + ((lr >> 1) << 6) + qA;
  const int bBase = (wn << 5) + ((lr >> 1) << 6) + qA;

  // staging lane math (derived + element-verified against the reader):
  // thread (wave w, lane l), chunk ch writes 16B at phys
  // (P = ch*64 + w*8 + (l>>3), q8 = l&7); source logical
  // R = ch*128 + w*16 + 2*(l>>3) + (u>>2), k = (u&3)*8, u = (l&7)^(l>>3).
  const int u    = (lane & 7) ^ (lane >> 3);
  const int srcR = 2 * (lane >> 3) + (u >> 2);
  const int srcK = (u & 3) * 8;
  const int sdst = wave * 512;   // elems; + ch*4096

  auto stage = [&](int kt, int b) {   // stages A AND B tile kt (4 gloads)
    #pragma unroll
    for (int ch = 0; ch < 2; ++ch) {
      const size_t roff = (size_t)(ch * 128 + wave * 16 + srcR) * K
                        + (size_t)kt * 32 + srcK;
      gload16(A + roff, shm + b * 8192 + ch * 4096 + sdst);
      gload16(B + roff, shm + 32768 + b * 8192 + ch * 4096 + sdst);
    }
  };

  f32x4 acc[8][4];
  #pragma unroll
  for (int m = 0; m < 8; ++m)
    #pragma unroll
    for (int n = 0; n < 4; ++n) acc[m][n] = (f32x4){0.f, 0.f, 0.f, 0.f};

  // prologue: stage tiles 0,1,2 (12 loads); drain tile 0 (keep 8); publish.
  stage(0, 0);
  stage(1, 1);
  stage(2, 2);
  VMW8
  __builtin_amdgcn_sched_barrier(0);
  __builtin_amdgcn_s_barrier();

  short8 bf[4];
  for (int t = 0; t < NT; ++t) {
    const int b  = t & 3;
    const int tp = (t + 3 < NT) ? (t + 3) : (NT - 1);
    short8 a00 = LDA32(b, 0, 0), a01 = LDA32(b, 0, 1);
    short8 a02 = LDA32(b, 0, 2), a03 = LDA32(b, 0, 3);
    short8 a10 = LDA32(b, 1, 0), a11 = LDA32(b, 1, 1);
    short8 a12 = LDA32(b, 1, 2), a13 = LDA32(b, 1, 3);
    bf[0] = LDB32(b, 0); bf[1] = LDB32(b, 1);
    bf[2] = LDB32(b, 2); bf[3] = LDB32(b, 3);
    stage(tp, (t + 3) & 3);
    asm volatile("s_waitcnt lgkmcnt(0)" ::: "memory");
    __builtin_amdgcn_sched_barrier(0);
    __builtin_amdgcn_s_setprio(1);
    MFMA16(0, a00, a01, a02, a03)
    MFMA16(1, a10, a11, a12, a13)
    __builtin_amdgcn_s_setprio(0);
    __builtin_amdgcn_sched_barrier(0);
    VMW8
    __builtin_amdgcn_s_barrier();
  }

  // epilogue (D^T layout, r7-verified): 16 x 8B vector stores
  const int lcc = (lane >> 4) * 4;
  s16* Hp = HOut + (size_t)e * C_ * I_;
  const int ibase = bn * 128 + (wn >> 1);
  #pragma unroll
  for (int m = 0; m < 8; ++m) {
    const int row = bm * 256 + wm + m * 16 + lr;
    #pragma unroll
    for (int p = 0; p < 2; ++p) {
      const int col = ibase + p * 16 + lcc;
      s16 o4[4];
      #pragma unroll
      for (int q = 0; q < 4; ++q) {
        float g = acc[m][2 * p][q], uv = acc[m][2 * p + 1][q];
        float sg = 1.0f / (1.0f + __expf(-g));
        o4[q] = f2bf(g * sg * uv);
      }
      *(short4v*)(Hp + (size_t)row * I_ + col) = *(short4v*)o4;
    }
  }
}

// ===========================================================================
// gemm_dn: down GEMM — r11 structure FROZEN (control).
// 256x256 tile, BK=64, 8-phase, 16x16x32 swapped-D^T, 128 KiB LDS.
// ===========================================================================
#define LDAF(B, MH, M, CX) \
  (*(const short8*)(shm + (B)*16384 + ((wm + (MH)*64 + (M)*16 + lr) << 6) + (CX)))
#define LDBF(B, N, CX) \
  (*(const short8*)(shm + 32768 + (B)*16384 + ((wn + (N)*16 + lr) << 6) + (CX)))

#define PHASE(B, MH, CX, RDB, STMT, WV)                                      \
  {                                                                          \
    short8 af0 = LDAF(B, MH, 0, CX);                                         \
    short8 af1 = LDAF(B, MH, 1, CX);                                         \
    short8 af2 = LDAF(B, MH, 2, CX);                                         \
    short8 af3 = LDAF(B, MH, 3, CX);                                         \
    if (RDB) {                                                               \
      bf[0] = LDBF(B, 0, CX); bf[1] = LDBF(B, 1, CX);                        \
      bf[2] = LDBF(B, 2, CX); bf[3] = LDBF(B, 3, CX);                        \
    }                                                                        \
    STMT                                                                     \
    __builtin_amdgcn_sched_barrier(0);                                       \
    __builtin_amdgcn_s_barrier();                                            \
    asm volatile("s_waitcnt lgkmcnt(0)" ::: "memory");                       \
    __builtin_amdgcn_sched_barrier(0);                                       \
    __builtin_amdgcn_s_setprio(1);                                           \
    MFMA16(MH, af0, af1, af2, af3)                                           \
    __builtin_amdgcn_s_setprio(0);                                           \
    __builtin_amdgcn_sched_barrier(0);                                       \
    WV                                                                       \
    __builtin_amdgcn_s_barrier();                                            \
  }

__global__ __launch_bounds__(512, 2) void gemm_dn(
    const s16* __restrict__ Abase, const s16* __restrict__ Bbase,
    float* __restrict__ FOut)
{
  constexpr int K  = I_;     // 4096
  constexpr int NB = H_;     // 1024
  constexpr int NT = K / 64;
  constexpr int TN = NB / 256;
  constexpr int TM = C_ / 256;
  constexpr int NWG = TM * TN;

  __shared__ s16 shm[65536];

  const int tid  = threadIdx.x;
  const int wave = tid >> 6, lane = tid & 63;
  const int e    = blockIdx.z;

  const int bid = blockIdx.x;
  const int swz = (bid & 7) * (NWG / 8) + (bid >> 3);
  const int bm = swz / TN, bn = swz % TN;

  const s16* A = Abase + (size_t)e * C_ * K + (size_t)bm * 256 * K;
  const s16* B = Bbase + (size_t)e * NB * K + (size_t)bn * 256 * K;

  const int wm  = (wave >> 2) * 128;
  const int wn  = (wave & 3) * 64;
  const int lr  = lane & 15;
  const int lkb = (lane >> 4) * 8;
  const int xr  = (lr & 7) << 3;
  const int cx0 = lkb ^ xr;
  const int cx1 = (32 + lkb) ^ xr;

  const int srow = tid >> 3;
  const int scol = ((tid & 7) ^ (srow & 7)) * 8;
  const size_t stoff = (size_t)srow * K + scol;
  const int sdst = wave * 512;

  auto stageA = [&](int kt, int b) {
    #pragma unroll
    for (int h = 0; h < 2; ++h)
      #pragma unroll
      for (int ll = 0; ll < 2; ++ll)
        gload16(A + (size_t)(h * 128 + ll * 64) * K + (size_t)kt * 64 + stoff,
                shm + b * 16384 + h * 8192 + ll * 4096 + sdst);
  };
  auto stageB = [&](int kt, int b) {
    #pragma unroll
    for (int h = 0; h < 2; ++h)
      #pragma unroll
      for (int ll = 0; ll < 2; ++ll)
        gload16(B + (size_t)(h * 128 + ll * 64) * K + (size_t)kt * 64 + stoff,
                shm + 32768 + b * 16384 + h * 8192 + ll * 4096 + sdst);
  };

  f32x4 acc[8][4];
  #pragma unroll
  for (int m = 0; m < 8; ++m)
    #pragma unroll
    for (int n = 0; n < 4; ++n) acc[m][n] = (f32x4){0.f, 0.f, 0.f, 0.f};

  stageB(0, 0);
  stageA(0, 0);
  stageB(1, 1);
  VMW4
  __builtin_amdgcn_sched_barrier(0);
  __builtin_amdgcn_s_barrier();

  short8 bf[4];
  for (int i = 0; i < NT / 2; ++i) {
    const int t1 = 2 * i + 1;
    const int t2 = (2 * i + 2 < NT) ? (2 * i + 2) : (NT - 1);
    const int t3 = (2 * i + 3 < NT) ? (2 * i + 3) : (NT - 1);
    PHASE(0, 0, cx0, 1, { stageA(t1, 1); }, )
    PHASE(0, 1, cx0, 0, {}, )
    PHASE(0, 0, cx1, 1, {}, )
    PHASE(0, 1, cx1, 0, { stageB(t2, 0); }, VMW4)
    PHASE(1, 0, cx0, 1, { stageA(t2, 0); }, )
    PHASE(1, 1, cx0, 0, {}, )
    PHASE(1, 0, cx1, 1, {}, )
    PHASE(1, 1, cx1, 0, { stageB(t3, 1); }, VMW4)
  }

  const int lcc = (lane >> 4) * 4;
  float* Op = FOut + (size_t)e * C_ * H_;
  #pragma unroll
  for (int m = 0; m < 8; ++m) {
    const int row = bm * 256 + wm + m * 16 + lr;
    #pragma unroll
    for (int n = 0; n < 4; ++n) {
      const int col = bn * 256 + wn + n * 16 + lcc;
      *(float4v*)(Op + (size_t)row * H_ + col) = acc[m][n];
    }
  }
}

// ---------------------------------------------------------------------------
extern "C" void kernel_launch(void* const* d_in, const int* in_sizes, int n_in,
                              void* d_out, int out_size, void* d_ws, size_t ws_size,
                              hipStream_t stream) {
  const float* x  = (const float*)d_in[0];
  const float* Wg = (const float*)d_in[1];
  const float* Wu = (const float*)d_in[2];
  const float* Wd = (const float*)d_in[3];
  float* out = (float*)d_out;

  const size_t szX  = (size_t)C_ * H_;
  const size_t szGU = (size_t)2 * I_ * H_;
  const size_t szWd = (size_t)H_ * I_;
  const size_t szH  = (size_t)C_ * I_;

  const size_t needFull = 2 * E_ * (szX + szGU + szWd + szH);   // 512 MiB

  constexpr int GU_BLK = (C_ / 256) * (2 * I_ / 256);   // 16 x 32 = 512
  constexpr int DN_BLK = (C_ / 256) * (H_ / 256);       // 64

  if (ws_size >= needFull) {
    s16* xb  = (s16*)d_ws;                  // [E][C][H]
    s16* Wgu = xb  + E_ * szX;              // [E][2I][H] interleaved
    s16* WdT = Wgu + E_ * szGU;             // [E][H][I]
    s16* hbf = WdT + E_ * szWd;             // [E][C][I]

    prep_kernel<<<dim3(1024, E_, 4), 256, 0, stream>>>(
        x, Wg, Wu, Wd, xb, Wgu, WdT);
    gemm_gu<<<dim3(GU_BLK, 1, E_), 512, 0, stream>>>(
        xb, Wgu, hbf);
    gemm_dn<<<dim3(DN_BLK, 1, E_), 512, 0, stream>>>(
        hbf, WdT, out);
  } else {
    // per-expert fallback (67 MiB workspace), same kernels with gridZ=1
    s16* xb  = (s16*)d_ws;
    s16* Wgu = xb  + szX;
    s16* WdT = Wgu + szGU;
    s16* hbf = WdT + szWd;

    for (int e = 0; e < E_; ++e) {
      prep_kernel<<<dim3(1024, 1, 4), 256, 0, stream>>>(
          x + e * szX, Wg + e * szWd, Wu + e * szWd, Wd + e * szWd,
          xb, Wgu, WdT);
      gemm_gu<<<dim3(GU_BLK, 1, 1), 512, 0, stream>>>(
          xb, Wgu, hbf);
      gemm_dn<<<dim3(DN_BLK, 1, 1), 512, 0, stream>>>(
          hbf, WdT, out + e * szX);
    }
  }
}

// Round 14
// 958.307 us; speedup vs baseline: 1.0336x; 1.0336x over previous
//
#include <hip/hip_runtime.h>
#include <hip/hip_bf16.h>
#include <stdint.h>
#include <stddef.h>

#define E_ 8
#define C_ 4096
#define H_ 1024
#define I_ 4096

typedef short s16;
typedef __attribute__((ext_vector_type(8))) short short8;   // 8 bf16 (4 VGPRs)
typedef __attribute__((ext_vector_type(4))) short short4v;  // 4 bf16 (8B)
typedef __attribute__((ext_vector_type(4))) float f32x4;    // MFMA C/D frag
typedef __attribute__((ext_vector_type(4))) float float4v;

__device__ __forceinline__ s16 f2bf(float f) {
  union { __hip_bfloat16 h; s16 s; } u;
  u.h = __float2bfloat16(f);
  return u.s;
}

// async global->LDS, 16B per lane. LDS dest is wave-uniform base + lane*16.
__device__ __forceinline__ void gload16(const void* gsrc, void* ldst) {
  __builtin_amdgcn_global_load_lds(
      (const __attribute__((address_space(1))) void*)gsrc,
      (__attribute__((address_space(3))) void*)ldst, 16, 0, 0);
}

// ---------------------------------------------------------------------------
// prep: expert = blockIdx.y   (FROZEN since r3; ~HBM roofline)
// z=0: x fp32 -> bf16
// z=1: Wg [H][I] -> interleaved Wgu rows (gate block)   [2I][H] bf16
// z=2: Wu -> interleaved Wgu rows (up block)
// z=3: Wd [I][H] -> WdT [H][I] bf16
// Interleave: real col i -> row (i&~15)*2 + (i&15) (+16 for up).
// ---------------------------------------------------------------------------
__global__ __launch_bounds__(256) void prep_kernel(
    const float* __restrict__ x, const float* __restrict__ Wg,
    const float* __restrict__ Wu, const float* __restrict__ Wd,
    s16* __restrict__ xb, s16* __restrict__ Wgu, s16* __restrict__ WdT)
{
  __shared__ float tile[64][65];
  const int t = threadIdx.x;
  const int z = blockIdx.z;
  const size_t e = blockIdx.y;

  if (z == 0) {
    size_t base = e * (size_t)C_ * H_ + ((size_t)blockIdx.x * 256 + t) * 16;
    for (int j = 0; j < 16; j += 8) {
      float4v v0 = *(const float4v*)(x + base + j);
      float4v v1 = *(const float4v*)(x + base + j + 4);
      s16 o[8];
      o[0] = f2bf(v0[0]); o[1] = f2bf(v0[1]); o[2] = f2bf(v0[2]); o[3] = f2bf(v0[3]);
      o[4] = f2bf(v1[0]); o[5] = f2bf(v1[1]); o[6] = f2bf(v1[2]); o[7] = f2bf(v1[3]);
      *(short8*)(xb + base + j) = *(short8*)o;
    }
    return;
  }

  const float* src; int Cc;
  if (z == 1)      { src = Wg + e * (size_t)H_ * I_; Cc = I_; }
  else if (z == 2) { src = Wu + e * (size_t)H_ * I_; Cc = I_; }
  else             { src = Wd + e * (size_t)H_ * I_; Cc = H_; }

  const int tpr  = Cc >> 6;
  const int trow = blockIdx.x / tpr;
  const int tcol = blockIdx.x % tpr;

  const int c = t & 63, rq = t >> 6;
  for (int i = 0; i < 16; ++i) {
    int r = rq * 16 + i;
    tile[r][c] = src[(size_t)(trow * 64 + r) * Cc + tcol * 64 + c];
  }
  __syncthreads();

  const int ro = t >> 2, cb = (t & 3) * 16;
  s16 o[16];
  for (int j = 0; j < 16; ++j) o[j] = f2bf(tile[cb + j][ro]);

  const int i0 = tcol * 64 + ro;
  s16* op;
  if (z == 3) {
    op = WdT + e * (size_t)H_ * I_ + (size_t)i0 * I_ + trow * 64 + cb;
  } else {
    int grow = ((i0 & ~15) << 1) + (i0 & 15) + ((z == 2) ? 16 : 0);
    op = Wgu + e * (size_t)2 * I_ * H_ + (size_t)grow * H_ + trow * 64 + cb;
  }
  *(short8*)op       = *(short8*)&o[0];
  *(short8*)(op + 8) = *(short8*)&o[8];
}

// ===========================================================================
// Shared: r7's HW-verified zero-conflict reader + swapped-operand (D^T)
// 16x16x32 MFMA. D^T map: out-row = ... + m*16 + (lane&15),
// out-col = ... + n*16 + (lane>>4)*4 + q (q=0..3 consecutive -> vector store).
// ===========================================================================
#define MFMA16(MH, A0, A1, A2, A3)                                                            \
  acc[(MH)*4+0][0] = __builtin_amdgcn_mfma_f32_16x16x32_bf16(bf[0], A0, acc[(MH)*4+0][0],0,0,0); \
  acc[(MH)*4+0][1] = __builtin_amdgcn_mfma_f32_16x16x32_bf16(bf[1], A0, acc[(MH)*4+0][1],0,0,0); \
  acc[(MH)*4+0][2] = __builtin_amdgcn_mfma_f32_16x16x32_bf16(bf[2], A0, acc[(MH)*4+0][2],0,0,0); \
  acc[(MH)*4+0][3] = __builtin_amdgcn_mfma_f32_16x16x32_bf16(bf[3], A0, acc[(MH)*4+0][3],0,0,0); \
  acc[(MH)*4+1][0] = __builtin_amdgcn_mfma_f32_16x16x32_bf16(bf[0], A1, acc[(MH)*4+1][0],0,0,0); \
  acc[(MH)*4+1][1] = __builtin_amdgcn_mfma_f32_16x16x32_bf16(bf[1], A1, acc[(MH)*4+1][1],0,0,0); \
  acc[(MH)*4+1][2] = __builtin_amdgcn_mfma_f32_16x16x32_bf16(bf[2], A1, acc[(MH)*4+1][2],0,0,0); \
  acc[(MH)*4+1][3] = __builtin_amdgcn_mfma_f32_16x16x32_bf16(bf[3], A1, acc[(MH)*4+1][3],0,0,0); \
  acc[(MH)*4+2][0] = __builtin_amdgcn_mfma_f32_16x16x32_bf16(bf[0], A2, acc[(MH)*4+2][0],0,0,0); \
  acc[(MH)*4+2][1] = __builtin_amdgcn_mfma_f32_16x16x32_bf16(bf[1], A2, acc[(MH)*4+2][1],0,0,0); \
  acc[(MH)*4+2][2] = __builtin_amdgcn_mfma_f32_16x16x32_bf16(bf[2], A2, acc[(MH)*4+2][2],0,0,0); \
  acc[(MH)*4+2][3] = __builtin_amdgcn_mfma_f32_16x16x32_bf16(bf[3], A2, acc[(MH)*4+2][3],0,0,0); \
  acc[(MH)*4+3][0] = __builtin_amdgcn_mfma_f32_16x16x32_bf16(bf[0], A3, acc[(MH)*4+3][0],0,0,0); \
  acc[(MH)*4+3][1] = __builtin_amdgcn_mfma_f32_16x16x32_bf16(bf[1], A3, acc[(MH)*4+3][1],0,0,0); \
  acc[(MH)*4+3][2] = __builtin_amdgcn_mfma_f32_16x16x32_bf16(bf[2], A3, acc[(MH)*4+3][2],0,0,0); \
  acc[(MH)*4+3][3] = __builtin_amdgcn_mfma_f32_16x16x32_bf16(bf[3], A3, acc[(MH)*4+3][3],0,0,0);

#define VMW4 asm volatile("s_waitcnt vmcnt(4)" ::: "memory");

#define LDAF(B, MH, M, CX) \
  (*(const short8*)(shm + (B)*16384 + ((wm + (MH)*64 + (M)*16 + lr) << 6) + (CX)))
#define LDBF(B, N, CX) \
  (*(const short8*)(shm + 32768 + (B)*16384 + ((wn + (N)*16 + lr) << 6) + (CX)))

#define PHASE(B, MH, CX, RDB, STMT, WV)                                      \
  {                                                                          \
    short8 af0 = LDAF(B, MH, 0, CX);                                         \
    short8 af1 = LDAF(B, MH, 1, CX);                                         \
    short8 af2 = LDAF(B, MH, 2, CX);                                         \
    short8 af3 = LDAF(B, MH, 3, CX);                                         \
    if (RDB) {                                                               \
      bf[0] = LDBF(B, 0, CX); bf[1] = LDBF(B, 1, CX);                        \
      bf[2] = LDBF(B, 2, CX); bf[3] = LDBF(B, 3, CX);                        \
    }                                                                        \
    STMT                                                                     \
    __builtin_amdgcn_sched_barrier(0);                                       \
    __builtin_amdgcn_s_barrier();                                            \
    asm volatile("s_waitcnt lgkmcnt(0)" ::: "memory");                       \
    __builtin_amdgcn_sched_barrier(0);                                       \
    __builtin_amdgcn_s_setprio(1);                                           \
    MFMA16(MH, af0, af1, af2, af3)                                           \
    __builtin_amdgcn_s_setprio(0);                                           \
    __builtin_amdgcn_sched_barrier(0);                                       \
    WV                                                                       \
    __builtin_amdgcn_s_barrier();                                            \
  }

// ===========================================================================
// gemm_gu: gateup — r7 configuration EXACTLY (measured session-best).
// 256x256 tile, BK=64, 8 waves, 128 KiB LDS dbuf, 8-phase counted-vmcnt,
// r4 fetch-optimal per-XCD partition, D^T vector epilogue with fused silu.
// ===========================================================================
__global__ __launch_bounds__(512, 2) void gemm_gu(
    const s16* __restrict__ Abase, const s16* __restrict__ Bbase,
    s16* __restrict__ HOut)
{
  constexpr int K  = H_;     // 1024
  constexpr int NB = 2 * I_; // 8192
  constexpr int NT = K / 64; // 16

  __shared__ s16 shm[65536];

  const int tid  = threadIdx.x;
  const int wave = tid >> 6, lane = tid & 63;
  const int e    = blockIdx.z;

  // r4 fetch-optimal per-XCD partition: 8bn x 8bm per XCD, bn-inner.
  const int bid = blockIdx.x;
  const int xcd = bid & 7;
  const int idx = bid >> 3;                // 0..63
  const int bn = (xcd & 3) * 8 + (idx & 7);
  const int bm = (xcd >> 2) * 8 + (idx >> 3);

  const s16* A = Abase + (size_t)e * C_ * K + (size_t)bm * 256 * K;
  const s16* B = Bbase + (size_t)e * NB * K + (size_t)bn * 256 * K;

  const int wm  = (wave >> 2) * 128;
  const int wn  = (wave & 3) * 64;
  const int lr  = lane & 15;
  const int lkb = (lane >> 4) * 8;
  const int xr  = (lr & 7) << 3;             // T2 read-side XOR
  const int cx0 = lkb ^ xr;
  const int cx1 = (32 + lkb) ^ xr;

  const int srow = tid >> 3;
  const int scol = ((tid & 7) ^ (srow & 7)) * 8;   // T2 write-side XOR
  const size_t stoff = (size_t)srow * K + scol;
  const int sdst = wave * 512;

  auto stageA = [&](int kt, int b) {
    #pragma unroll
    for (int h = 0; h < 2; ++h)
      #pragma unroll
      for (int ll = 0; ll < 2; ++ll)
        gload16(A + (size_t)(h * 128 + ll * 64) * K + (size_t)kt * 64 + stoff,
                shm + b * 16384 + h * 8192 + ll * 4096 + sdst);
  };
  auto stageB = [&](int kt, int b) {
    #pragma unroll
    for (int h = 0; h < 2; ++h)
      #pragma unroll
      for (int ll = 0; ll < 2; ++ll)
        gload16(B + (size_t)(h * 128 + ll * 64) * K + (size_t)kt * 64 + stoff,
                shm + 32768 + b * 16384 + h * 8192 + ll * 4096 + sdst);
  };

  f32x4 acc[8][4];
  #pragma unroll
  for (int m = 0; m < 8; ++m)
    #pragma unroll
    for (int n = 0; n < 4; ++n) acc[m][n] = (f32x4){0.f, 0.f, 0.f, 0.f};

  // prologue: tile0 (buf0) fully + tile1.B (buf1); t1.B left in flight
  stageB(0, 0);
  stageA(0, 0);
  stageB(1, 1);
  VMW4
  __builtin_amdgcn_sched_barrier(0);
  __builtin_amdgcn_s_barrier();

  short8 bf[4];
  // r7 ledger: issue t1.A(ph1) t2.B(ph4) t2.A(ph5) t3.B(ph8); VMW4 at
  // ph4/ph8 -> t1 done before ph5 reads buf1, t2 done before next ph1.
  for (int i = 0; i < NT / 2; ++i) {
    const int t1 = 2 * i + 1;
    const int t2 = (2 * i + 2 < NT) ? (2 * i + 2) : (NT - 1);
    const int t3 = (2 * i + 3 < NT) ? (2 * i + 3) : (NT - 1);
    PHASE(0, 0, cx0, 1, { stageA(t1, 1); }, )
    PHASE(0, 1, cx0, 0, {}, )
    PHASE(0, 0, cx1, 1, {}, )
    PHASE(0, 1, cx1, 0, { stageB(t2, 0); }, VMW4)
    PHASE(1, 0, cx0, 1, { stageA(t2, 0); }, )
    PHASE(1, 1, cx0, 0, {}, )
    PHASE(1, 0, cx1, 1, {}, )
    PHASE(1, 1, cx1, 0, { stageB(t3, 1); }, VMW4)
  }

  // epilogue (D^T layout): row = m*16+(lane&15), col = n*16+(lane>>4)*4+q
  const int lcc = (lane >> 4) * 4;
  s16* Hp = HOut + (size_t)e * C_ * I_;
  const int ibase = bn * 128 + (wn >> 1);
  #pragma unroll
  for (int m = 0; m < 8; ++m) {
    const int row = bm * 256 + wm + m * 16 + lr;
    #pragma unroll
    for (int p = 0; p < 2; ++p) {
      const int col = ibase + p * 16 + lcc;
      s16 o4[4];
      #pragma unroll
      for (int q = 0; q < 4; ++q) {
        float g = acc[m][2 * p][q], u = acc[m][2 * p + 1][q];
        float sg = 1.0f / (1.0f + __expf(-g));
        o4[q] = f2bf(g * sg * u);
      }
      *(short4v*)(Hp + (size_t)row * I_ + col) = *(short4v*)o4;
    }
  }
}

// ===========================================================================
// gemm_dn: down GEMM — r7 structure FROZEN.
// 256x256 tile, BK=64, 8-phase, 16x16x32 swapped-D^T, 128 KiB LDS.
// ===========================================================================
__global__ __launch_bounds__(512, 2) void gemm_dn(
    const s16* __restrict__ Abase, const s16* __restrict__ Bbase,
    float* __restrict__ FOut)
{
  constexpr int K  = I_;     // 4096
  constexpr int NB = H_;     // 1024
  constexpr int NT = K / 64;
  constexpr int TN = NB / 256;
  constexpr int TM = C_ / 256;
  constexpr int NWG = TM * TN;

  __shared__ s16 shm[65536];

  const int tid  = threadIdx.x;
  const int wave = tid >> 6, lane = tid & 63;
  const int e    = blockIdx.z;

  const int bid = blockIdx.x;
  const int swz = (bid & 7) * (NWG / 8) + (bid >> 3);
  const int bm = swz / TN, bn = swz % TN;

  const s16* A = Abase + (size_t)e * C_ * K + (size_t)bm * 256 * K;
  const s16* B = Bbase + (size_t)e * NB * K + (size_t)bn * 256 * K;

  const int wm  = (wave >> 2) * 128;
  const int wn  = (wave & 3) * 64;
  const int lr  = lane & 15;
  const int lkb = (lane >> 4) * 8;
  const int xr  = (lr & 7) << 3;
  const int cx0 = lkb ^ xr;
  const int cx1 = (32 + lkb) ^ xr;

  const int srow = tid >> 3;
  const int scol = ((tid & 7) ^ (srow & 7)) * 8;
  const size_t stoff = (size_t)srow * K + scol;
  const int sdst = wave * 512;

  auto stageA = [&](int kt, int b) {
    #pragma unroll
    for (int h = 0; h < 2; ++h)
      #pragma unroll
      for (int ll = 0; ll < 2; ++ll)
        gload16(A + (size_t)(h * 128 + ll * 64) * K + (size_t)kt * 64 + stoff,
                shm + b * 16384 + h * 8192 + ll * 4096 + sdst);
  };
  auto stageB = [&](int kt, int b) {
    #pragma unroll
    for (int h = 0; h < 2; ++h)
      #pragma unroll
      for (int ll = 0; ll < 2; ++ll)
        gload16(B + (size_t)(h * 128 + ll * 64) * K + (size_t)kt * 64 + stoff,
                shm + 32768 + b * 16384 + h * 8192 + ll * 4096 + sdst);
  };

  f32x4 acc[8][4];
  #pragma unroll
  for (int m = 0; m < 8; ++m)
    #pragma unroll
    for (int n = 0; n < 4; ++n) acc[m][n] = (f32x4){0.f, 0.f, 0.f, 0.f};

  stageB(0, 0);
  stageA(0, 0);
  stageB(1, 1);
  VMW4
  __builtin_amdgcn_sched_barrier(0);
  __builtin_amdgcn_s_barrier();

  short8 bf[4];
  for (int i = 0; i < NT / 2; ++i) {
    const int t1 = 2 * i + 1;
    const int t2 = (2 * i + 2 < NT) ? (2 * i + 2) : (NT - 1);
    const int t3 = (2 * i + 3 < NT) ? (2 * i + 3) : (NT - 1);
    PHASE(0, 0, cx0, 1, { stageA(t1, 1); }, )
    PHASE(0, 1, cx0, 0, {}, )
    PHASE(0, 0, cx1, 1, {}, )
    PHASE(0, 1, cx1, 0, { stageB(t2, 0); }, VMW4)
    PHASE(1, 0, cx0, 1, { stageA(t2, 0); }, )
    PHASE(1, 1, cx0, 0, {}, )
    PHASE(1, 0, cx1, 1, {}, )
    PHASE(1, 1, cx1, 0, { stageB(t3, 1); }, VMW4)
  }

  const int lcc = (lane >> 4) * 4;
  float* Op = FOut + (size_t)e * C_ * H_;
  #pragma unroll
  for (int m = 0; m < 8; ++m) {
    const int row = bm * 256 + wm + m * 16 + lr;
    #pragma unroll
    for (int n = 0; n < 4; ++n) {
      const int col = bn * 256 + wn + n * 16 + lcc;
      *(float4v*)(Op + (size_t)row * H_ + col) = acc[m][n];
    }
  }
}

// ---------------------------------------------------------------------------
extern "C" void kernel_launch(void* const* d_in, const int* in_sizes, int n_in,
                              void* d_out, int out_size, void* d_ws, size_t ws_size,
                              hipStream_t stream) {
  const float* x  = (const float*)d_in[0];
  const float* Wg = (const float*)d_in[1];
  const float* Wu = (const float*)d_in[2];
  const float* Wd = (const float*)d_in[3];
  float* out = (float*)d_out;

  const size_t szX  = (size_t)C_ * H_;
  const size_t szGU = (size_t)2 * I_ * H_;
  const size_t szWd = (size_t)H_ * I_;
  const size_t szH  = (size_t)C_ * I_;

  const size_t needFull = 2 * E_ * (szX + szGU + szWd + szH);   // 512 MiB

  constexpr int GU_BLK = (C_ / 256) * (2 * I_ / 256);   // 512
  constexpr int DN_BLK = (C_ / 256) * (H_ / 256);       // 64

  if (ws_size >= needFull) {
    s16* xb  = (s16*)d_ws;                  // [E][C][H]
    s16* Wgu = xb  + E_ * szX;              // [E][2I][H] interleaved
    s16* WdT = Wgu + E_ * szGU;             // [E][H][I]
    s16* hbf = WdT + E_ * szWd;             // [E][C][I]

    prep_kernel<<<dim3(1024, E_, 4), 256, 0, stream>>>(
        x, Wg, Wu, Wd, xb, Wgu, WdT);
    gemm_gu<<<dim3(GU_BLK, 1, E_), 512, 0, stream>>>(
        xb, Wgu, hbf);
    gemm_dn<<<dim3(DN_BLK, 1, E_), 512, 0, stream>>>(
        hbf, WdT, out);
  } else {
    // per-expert fallback (67 MiB workspace), same kernels with gridZ=1
    s16* xb  = (s16*)d_ws;
    s16* Wgu = xb  + szX;
    s16* WdT = Wgu + szGU;
    s16* hbf = WdT + szWd;

    for (int e = 0; e < E_; ++e) {
      prep_kernel<<<dim3(1024, 1, 4), 256, 0, stream>>>(
          x + e * szX, Wg + e * szWd, Wu + e * szWd, Wd + e * szWd,
          xb, Wgu, WdT);
      gemm_gu<<<dim3(GU_BLK, 1, 1), 512, 0, stream>>>(
          xb, Wgu, hbf);
      gemm_dn<<<dim3(DN_BLK, 1, 1), 512, 0, stream>>>(
          hbf, WdT, out + e * szX);
    }
  }
}